// Round 1
// baseline (406.607 us; speedup 1.0000x reference)
//
#include <hip/hip_runtime.h>
#include <math.h>

// LinOSS layer, IM discretization. f32 throughout.
// Bt=16, L=4096, H=128, P=256.
// Pipeline:
//   k_coeff : per-p coefficients m11,m12,m21,m22,s1,s2 and Mchunk = M^CL
//   k_gemm1 : bu[m][p] = inputs[m][:] . Bc[p][:]  (complex out, real in)  -> ws
//   k_scanA : per (b,p,chunk) local recurrence from zero state -> chunk finals
//   k_scanB : cross-chunk recombination (x_init per chunk) via Mchunk
//   k_scanC : replay chunks from correct init, write x2 IN PLACE over bu
//   k_gemm2 : out[m][h] = Re( x2[m][:] . Cc[h][:] ) + in[m][h]*D[h]

constexpr int BTc = 16;
constexpr int Lc  = 4096;
constexpr int Hc  = 128;
constexpr int Pc  = 256;
constexpr int CL  = 64;            // chunk length
constexpr int NC  = Lc / CL;       // 64 chunks
constexpr int LOG2CL = 6;

// workspace layout (floats)
constexpr size_t CF_FLOATS  = 4096;                        // 10*Pc used
constexpr size_t BU_OFF     = CF_FLOATS;
constexpr size_t BU_FLOATS  = (size_t)BTc * Lc * Pc * 2;   // 33,554,432 (128 MB)
constexpr size_t LOC_OFF    = BU_OFF + BU_FLOATS;
constexpr size_t LOC_FLOATS = (size_t)BTc * NC * Pc * 4;   // 1,048,576 (4 MB)
constexpr size_t INIT_OFF   = LOC_OFF + LOC_FLOATS;
// total ~136 MB

// ---------------------------------------------------------------- coeffs
__global__ void k_coeff(const float* __restrict__ A_diag,
                        const float* __restrict__ steps,
                        float* __restrict__ cf) {
    int p = threadIdx.x;
    float a  = fmaxf(A_diag[p], 0.0f);
    float st = 1.0f / (1.0f + expf(-steps[p]));
    float s2a   = st * st * a;
    float schur = 1.0f / (1.0f + s2a);
    float m11 = 1.0f - s2a * schur;
    float m12 = -st * a * schur;
    float m21 = st * schur;
    float m22 = schur;
    cf[0*Pc+p] = m11;  cf[1*Pc+p] = m12;
    cf[2*Pc+p] = m21;  cf[3*Pc+p] = m22;
    cf[4*Pc+p] = m11 * st;   // s1 : f1 = s1*bu
    cf[5*Pc+p] = m21 * st;   // s2 : f2 = s2*bu
    // Mchunk = M^CL by repeated squaring
    float a11=m11, a12=m12, a21=m21, a22=m22;
    #pragma unroll
    for (int i = 0; i < LOG2CL; i++) {
        float b11 = a11*a11 + a12*a21;
        float b12 = a11*a12 + a12*a22;
        float b21 = a21*a11 + a22*a21;
        float b22 = a21*a12 + a22*a22;
        a11=b11; a12=b12; a21=b21; a22=b22;
    }
    cf[6*Pc+p]=a11; cf[7*Pc+p]=a12; cf[8*Pc+p]=a21; cf[9*Pc+p]=a22;
}

// ---------------------------------------------------------------- GEMM1
// bu[m][p] (complex) = sum_h in[m][h] * Bc[p][h]
// block tile: 64 m-rows x 64 complex-p. 256 threads, 4m x 4p complex each.
__global__ __launch_bounds__(256) void k_gemm1(const float* __restrict__ in,
                                               const float* __restrict__ Bw,
                                               float2* __restrict__ bu) {
    __shared__ float As[32][64];      // [k][m]      8 KB
    __shared__ float Bs[32][64][2];   // [k][p][c]  16 KB
    int tid = threadIdx.x;
    int tx = tid & 15, ty = tid >> 4;
    size_t m0 = (size_t)blockIdx.x * 64;
    int p0 = blockIdx.y * 64;
    float acc[4][4][2] = {};

    for (int k0 = 0; k0 < Hc; k0 += 32) {
        // stage A (transposed): in[m][k] -> As[k][m]
        {
            int row = tid >> 2;
            int colbase = (tid & 3) * 8;
            const float* ga = &in[(m0 + row) * Hc + k0 + colbase];
            float4 fa0 = *(const float4*)ga;
            float4 fa1 = *(const float4*)(ga + 4);
            As[colbase+0][row]=fa0.x; As[colbase+1][row]=fa0.y;
            As[colbase+2][row]=fa0.z; As[colbase+3][row]=fa0.w;
            As[colbase+4][row]=fa1.x; As[colbase+5][row]=fa1.y;
            As[colbase+6][row]=fa1.z; As[colbase+7][row]=fa1.w;
        }
        // stage B: Bw[p][h][c] -> Bs[k][p][c]
        {
            int p  = tid >> 2;
            int fo = (tid & 3) * 16;            // float offset within 64-float row segment
            const float* gb = &Bw[(size_t)(p0 + p) * (Hc*2) + k0*2 + fo];
            #pragma unroll
            for (int j = 0; j < 4; j++) {
                float4 f = *(const float4*)(gb + j*4);
                int kk = (fo >> 1) + j*2;
                Bs[kk  ][p][0] = f.x; Bs[kk  ][p][1] = f.y;
                Bs[kk+1][p][0] = f.z; Bs[kk+1][p][1] = f.w;
            }
        }
        __syncthreads();
        #pragma unroll 8
        for (int kk = 0; kk < 32; kk++) {
            float4 av = *(const float4*)&As[kk][ty*4];
            float am[4] = {av.x, av.y, av.z, av.w};
            float br[4], bi[4];
            #pragma unroll
            for (int pi = 0; pi < 4; pi++) {
                // p = tx + pi*16 : 16-lane-strided -> conflict-free b64 reads
                float2 bv = *(const float2*)&Bs[kk][tx + pi*16][0];
                br[pi] = bv.x; bi[pi] = bv.y;
            }
            #pragma unroll
            for (int mi = 0; mi < 4; mi++) {
                #pragma unroll
                for (int pi = 0; pi < 4; pi++) {
                    acc[mi][pi][0] = fmaf(am[mi], br[pi], acc[mi][pi][0]);
                    acc[mi][pi][1] = fmaf(am[mi], bi[pi], acc[mi][pi][1]);
                }
            }
        }
        __syncthreads();
    }
    // epilogue: float2 per (m,p)
    #pragma unroll
    for (int mi = 0; mi < 4; mi++) {
        size_t m = m0 + ty*4 + mi;
        #pragma unroll
        for (int pi = 0; pi < 4; pi++) {
            bu[m * Pc + p0 + tx + pi*16] = make_float2(acc[mi][pi][0], acc[mi][pi][1]);
        }
    }
}

// ---------------------------------------------------------------- scan A
__global__ __launch_bounds__(256) void k_scanA(const float2* __restrict__ bu,
                                               const float* __restrict__ cf,
                                               float4* __restrict__ loc) {
    int b = blockIdx.x / NC, c = blockIdx.x % NC;
    int p = threadIdx.x;
    float m11=cf[0*Pc+p], m12=cf[1*Pc+p], m21=cf[2*Pc+p], m22=cf[3*Pc+p];
    float s1 =cf[4*Pc+p], s2 =cf[5*Pc+p];
    float x1r=0.f, x1i=0.f, x2r=0.f, x2i=0.f;
    const float2* src = bu + ((size_t)(b*Lc + c*CL)) * Pc + p;
    #pragma unroll 4
    for (int l = 0; l < CL; l++) {
        float2 f = src[(size_t)l * Pc];
        float n1r = fmaf(m11,x1r, fmaf(m12,x2r, s1*f.x));
        float n1i = fmaf(m11,x1i, fmaf(m12,x2i, s1*f.y));
        float n2r = fmaf(m21,x1r, fmaf(m22,x2r, s2*f.x));
        float n2i = fmaf(m21,x1i, fmaf(m22,x2i, s2*f.y));
        x1r=n1r; x1i=n1i; x2r=n2r; x2i=n2i;
    }
    loc[(size_t)(b*NC + c) * Pc + p] = make_float4(x1r, x1i, x2r, x2i);
}

// ---------------------------------------------------------------- scan B
__global__ __launch_bounds__(256) void k_scanB(const float* __restrict__ cf,
                                               const float4* __restrict__ loc,
                                               float4* __restrict__ ini) {
    int b = blockIdx.x;
    int p = threadIdx.x;
    float A11=cf[6*Pc+p], A12=cf[7*Pc+p], A21=cf[8*Pc+p], A22=cf[9*Pc+p];
    float x1r=0.f, x1i=0.f, x2r=0.f, x2i=0.f;
    for (int c = 0; c < NC; c++) {
        size_t idx = (size_t)(b*NC + c) * Pc + p;
        ini[idx] = make_float4(x1r, x1i, x2r, x2i);
        float4 lo = loc[idx];
        float n1r = fmaf(A11,x1r, fmaf(A12,x2r, lo.x));
        float n1i = fmaf(A11,x1i, fmaf(A12,x2i, lo.y));
        float n2r = fmaf(A21,x1r, fmaf(A22,x2r, lo.z));
        float n2i = fmaf(A21,x1i, fmaf(A22,x2i, lo.w));
        x1r=n1r; x1i=n1i; x2r=n2r; x2i=n2i;
    }
}

// ---------------------------------------------------------------- scan C
// replay from correct init; write x2 in place over bu
__global__ __launch_bounds__(256) void k_scanC(float2* __restrict__ bu,
                                               const float* __restrict__ cf,
                                               const float4* __restrict__ ini) {
    int b = blockIdx.x / NC, c = blockIdx.x % NC;
    int p = threadIdx.x;
    float m11=cf[0*Pc+p], m12=cf[1*Pc+p], m21=cf[2*Pc+p], m22=cf[3*Pc+p];
    float s1 =cf[4*Pc+p], s2 =cf[5*Pc+p];
    float4 x0 = ini[(size_t)(b*NC + c) * Pc + p];
    float x1r=x0.x, x1i=x0.y, x2r=x0.z, x2i=x0.w;
    float2* ptr = bu + ((size_t)(b*Lc + c*CL)) * Pc + p;
    #pragma unroll 4
    for (int l = 0; l < CL; l++) {
        float2 f = ptr[(size_t)l * Pc];
        float n1r = fmaf(m11,x1r, fmaf(m12,x2r, s1*f.x));
        float n1i = fmaf(m11,x1i, fmaf(m12,x2i, s1*f.y));
        float n2r = fmaf(m21,x1r, fmaf(m22,x2r, s2*f.x));
        float n2i = fmaf(m21,x1i, fmaf(m22,x2i, s2*f.y));
        x1r=n1r; x1i=n1i; x2r=n2r; x2i=n2i;
        ptr[(size_t)l * Pc] = make_float2(x2r, x2i);
    }
}

// ---------------------------------------------------------------- GEMM2
// out[m][h] = sum_p ( Xre[m][p]*Cre[h][p] - Xim[m][p]*Cim[h][p] ) + in[m][h]*D[h]
// block tile: 64 m-rows x 64 h. 256 threads, 4m x 4h each.
__global__ __launch_bounds__(256) void k_gemm2(const float2* __restrict__ X,
                                               const float* __restrict__ Cw,
                                               const float* __restrict__ in,
                                               const float* __restrict__ Dw,
                                               float* __restrict__ out) {
    __shared__ float Xs[32][64][2];   // [k][m][c] 16 KB
    __shared__ float Cs[32][64][2];   // [k][h][c] 16 KB
    int tid = threadIdx.x;
    int tx = tid & 15, ty = tid >> 4;
    size_t m0 = (size_t)blockIdx.x * 64;
    int h0 = blockIdx.y * 64;
    float acc[4][4] = {};
    const float* Xf = (const float*)X;

    for (int k0 = 0; k0 < Pc; k0 += 32) {
        int row = tid >> 2;
        int fo  = (tid & 3) * 16;
        // stage X: X[m][p] (interleaved) -> Xs[k][m][c]
        {
            const float* gx = &Xf[((m0 + row) * Pc + k0) * 2 + fo];
            #pragma unroll
            for (int j = 0; j < 4; j++) {
                float4 f = *(const float4*)(gx + j*4);
                int kk = (fo >> 1) + j*2;
                Xs[kk  ][row][0] = f.x; Xs[kk  ][row][1] = f.y;
                Xs[kk+1][row][0] = f.z; Xs[kk+1][row][1] = f.w;
            }
        }
        // stage C: Cw[h][p][c] -> Cs[k][h][c]
        {
            const float* gc = &Cw[(size_t)(h0 + row) * (Pc*2) + k0*2 + fo];
            #pragma unroll
            for (int j = 0; j < 4; j++) {
                float4 f = *(const float4*)(gc + j*4);
                int kk = (fo >> 1) + j*2;
                Cs[kk  ][row][0] = f.x; Cs[kk  ][row][1] = f.y;
                Cs[kk+1][row][0] = f.z; Cs[kk+1][row][1] = f.w;
            }
        }
        __syncthreads();
        #pragma unroll 8
        for (int kk = 0; kk < 32; kk++) {
            float4 xv0 = *(const float4*)&Xs[kk][ty*4    ][0];
            float4 xv1 = *(const float4*)&Xs[kk][ty*4 + 2][0];
            float xr[4] = {xv0.x, xv0.z, xv1.x, xv1.z};
            float xi[4] = {xv0.y, xv0.w, xv1.y, xv1.w};
            float cr[4], ci[4];
            #pragma unroll
            for (int hi = 0; hi < 4; hi++) {
                float2 cv = *(const float2*)&Cs[kk][tx + hi*16][0];
                cr[hi] = cv.x; ci[hi] = cv.y;
            }
            #pragma unroll
            for (int mi = 0; mi < 4; mi++) {
                #pragma unroll
                for (int hi = 0; hi < 4; hi++) {
                    acc[mi][hi] = fmaf(xr[mi],  cr[hi], acc[mi][hi]);
                    acc[mi][hi] = fmaf(-xi[mi], ci[hi], acc[mi][hi]);
                }
            }
        }
        __syncthreads();
    }
    // epilogue: + in*D
    #pragma unroll
    for (int mi = 0; mi < 4; mi++) {
        size_t m = m0 + ty*4 + mi;
        #pragma unroll
        for (int hi = 0; hi < 4; hi++) {
            int h = h0 + tx + hi*16;
            out[m * Hc + h] = fmaf(in[m * Hc + h], Dw[h], acc[mi][hi]);
        }
    }
}

// ---------------------------------------------------------------- launch
extern "C" void kernel_launch(void* const* d_in, const int* in_sizes, int n_in,
                              void* d_out, int out_size, void* d_ws, size_t ws_size,
                              hipStream_t stream) {
    const float* in  = (const float*)d_in[0];
    const float* Ad  = (const float*)d_in[1];
    const float* Bw  = (const float*)d_in[2];
    const float* Cw  = (const float*)d_in[3];
    const float* Dw  = (const float*)d_in[4];
    const float* stp = (const float*)d_in[5];
    float* ws = (float*)d_ws;
    float*  cf  = ws;
    float2* bu  = (float2*)(ws + BU_OFF);
    float4* loc = (float4*)(ws + LOC_OFF);
    float4* ini = (float4*)(ws + INIT_OFF);
    float* out = (float*)d_out;

    k_coeff<<<1, 256, 0, stream>>>(Ad, stp, cf);
    k_gemm1<<<dim3((BTc*Lc)/64, Pc/64), 256, 0, stream>>>(in, Bw, bu);
    k_scanA<<<dim3(BTc*NC), 256, 0, stream>>>(bu, cf, loc);
    k_scanB<<<dim3(BTc), 256, 0, stream>>>(cf, loc, ini);
    k_scanC<<<dim3(BTc*NC), 256, 0, stream>>>(bu, cf, ini);
    k_gemm2<<<dim3((BTc*Lc)/64, Hc/64), 256, 0, stream>>>(bu, Cw, in, Dw, out);
}

// Round 2
// 171.934 us; speedup vs baseline: 2.3649x; 2.3649x over previous
//
#include <hip/hip_runtime.h>
#include <math.h>

// LinOSS layer (IM), fused MFMA pipeline. Bt=16, L=4096, H=128, P=256.
//   k_prep  : coefficients + bf16 fragment-linear weight packs (B, C')
//   k_pass<1>: per (b,chunk): stage U, GEMM1 (bf16 MFMA) -> LDS, local scan
//              from zero -> chunk-final states (loc). bu never hits HBM.
//   k_scanB : per b: compose chunk finals with Mchunk=M^64 -> per-chunk inits
//   k_pass<2>: recompute GEMM1, replay scan from inits, x2->bf16 in LDS,
//              GEMM2 (MFMA, K=512 with -ci trick) + in*D epilogue -> out.

constexpr int BTc = 16;
constexpr int Lc  = 4096;
constexpr int Hc  = 128;
constexpr int Pc  = 256;
constexpr int CL  = 64;
constexpr int NC  = Lc / CL;   // 64
constexpr int LOG2CL = 6;

typedef __attribute__((ext_vector_type(8))) short short8;
typedef __attribute__((ext_vector_type(4))) float f32x4;

// workspace byte offsets
constexpr size_t CF_OFF  = 0;                  // 10*256 floats used
constexpr size_t BF_OFF  = 16384;              // 65536 bf16: GEMM1 B frags
constexpr size_t CFR_OFF = BF_OFF + 131072;    // 65536 bf16: GEMM2 C' frags
constexpr size_t LOC_OFF = CFR_OFF + 131072;   // 16*64*512 float2 (4 MB)
constexpr size_t INI_OFF = LOC_OFF + 4194304;  // 4 MB

// LDS byte offsets (per block): U bf16 [64][128] swz | BU f32 [64][260] | XS bf16 [64][256] swz
constexpr int LDS_U  = 0;        // 16384 B
constexpr int LDS_BU = 16384;    // 66560 B  (pad 260 -> conflict-free scalar access)
constexpr int LDS_XS = 82944;    // 32768 B
constexpr int LDS_BYTES = 115712;

__device__ __forceinline__ unsigned short f2bf(float x) {
    unsigned u = __float_as_uint(x);
    u += 0x7fffu + ((u >> 16) & 1u);          // RNE
    return (unsigned short)(u >> 16);
}
__device__ __forceinline__ float bf2f(unsigned short h) {
    return __uint_as_float(((unsigned)h) << 16);
}
__device__ __forceinline__ f32x4 mfma16(short8 a, short8 b, f32x4 c) {
    return __builtin_amdgcn_mfma_f32_16x16x32_bf16(a, b, c, 0, 0, 0);
}

// ---------------------------------------------------------------- prep
// BF layout: idx = ((kt*32 + nfg)*64 + lane)*8 + j ; k=kt*32+(lane>>4)*8+j (h),
//            n=nfg*16+(lane&15) (512 = 2p+part). CF': k channel, h col, -ci.
__global__ __launch_bounds__(256) void k_prep(const float* __restrict__ A_diag,
                                              const float* __restrict__ steps,
                                              const float* __restrict__ Bw,
                                              const float* __restrict__ Cw,
                                              float* __restrict__ cf,
                                              unsigned short* __restrict__ BF,
                                              unsigned short* __restrict__ CFr) {
    int idx = blockIdx.x * 256 + threadIdx.x;   // 0..65535
    {   // GEMM1 B fragments
        int j = idx & 7, lane = (idx >> 3) & 63, nfg = (idx >> 9) & 31, kt = idx >> 14;
        int k = kt * 32 + (lane >> 4) * 8 + j;          // h in 0..127
        int n = nfg * 16 + (lane & 15);                 // 0..511
        int p = n >> 1, part = n & 1;
        BF[idx] = f2bf(Bw[(p * Hc + k) * 2 + part]);
    }
    {   // GEMM2 C' fragments
        int j = idx & 7, lane = (idx >> 3) & 63, nfg = (idx >> 9) & 7, ktG = idx >> 12;
        int k = ktG * 32 + (lane >> 4) * 8 + j;         // 0..511 channel
        int h = nfg * 16 + (lane & 15);
        int p = k >> 1, part = k & 1;
        float v = Cw[(h * Pc + p) * 2 + part];
        CFr[idx] = f2bf(part ? -v : v);
    }
    if (blockIdx.x == 0) {  // coefficients, one p per thread
        int p = threadIdx.x;
        float a  = fmaxf(A_diag[p], 0.0f);
        float st = 1.0f / (1.0f + expf(-steps[p]));
        float s2a   = st * st * a;
        float schur = 1.0f / (1.0f + s2a);
        float m11 = 1.0f - s2a * schur;
        float m12 = -st * a * schur;
        float m21 = st * schur;
        float m22 = schur;
        cf[0*Pc+p] = m11;  cf[1*Pc+p] = m12;
        cf[2*Pc+p] = m21;  cf[3*Pc+p] = m22;
        cf[4*Pc+p] = m11 * st;   // s1
        cf[5*Pc+p] = m21 * st;   // s2
        float a11=m11, a12=m12, a21=m21, a22=m22;
        #pragma unroll
        for (int i = 0; i < LOG2CL; i++) {
            float b11 = a11*a11 + a12*a21;
            float b12 = a11*a12 + a12*a22;
            float b21 = a21*a11 + a22*a21;
            float b22 = a21*a12 + a22*a22;
            a11=b11; a12=b12; a21=b21; a22=b22;
        }
        cf[6*Pc+p]=a11; cf[7*Pc+p]=a12; cf[8*Pc+p]=a21; cf[9*Pc+p]=a22;
    }
}

// ---------------------------------------------------------------- scan B
__global__ __launch_bounds__(512) void k_scanB(const float* __restrict__ cf,
                                               const float2* __restrict__ loc,
                                               float2* __restrict__ ini) {
    int b = blockIdx.x, n = threadIdx.x;
    int p = n >> 1;
    float A11=cf[6*Pc+p], A12=cf[7*Pc+p], A21=cf[8*Pc+p], A22=cf[9*Pc+p];
    float x1 = 0.f, x2 = 0.f;
    for (int c = 0; c < NC; c++) {
        size_t idx = ((size_t)(b * NC + c)) * 512 + n;
        ini[idx] = make_float2(x1, x2);
        float2 lv = loc[idx];
        float n1 = fmaf(A11, x1, fmaf(A12, x2, lv.x));
        float n2 = fmaf(A21, x1, fmaf(A22, x2, lv.y));
        x1 = n1; x2 = n2;
    }
}

// ---------------------------------------------------------------- fused pass
template<int PASS>
__global__ __launch_bounds__(512, 2) void k_pass(const float* __restrict__ in,
                                                 const float* __restrict__ cf,
                                                 const unsigned short* __restrict__ BF,
                                                 const unsigned short* __restrict__ CFr,
                                                 const float* __restrict__ Dw,
                                                 float2* __restrict__ loc,
                                                 const float2* __restrict__ ini,
                                                 float* __restrict__ out) {
    __shared__ float4 smem4[LDS_BYTES / 16];
    char* sm = (char*)smem4;
    float* BU = (float*)(sm + LDS_BU);

    int tid  = threadIdx.x;
    int lane = tid & 63;
    int w    = tid >> 6;            // wave 0..7
    int wm   = w >> 2, wn = w & 3;  // 2M x 4N wave grid
    int bc   = blockIdx.x;          // b*64 + c
    size_t mbase = (size_t)bc * CL; // == (b*Lc + c*CL) since Lc = NC*CL

    // ---- stage U: in[chunk] f32 -> bf16, XOR-swizzled chunks of 8 ----
    {
        int l   = tid >> 3;
        int kc0 = (tid & 7) * 2;
        const float* g = in + (mbase + l) * Hc + (tid & 7) * 16;
        float4 f0 = *(const float4*)(g);
        float4 f1 = *(const float4*)(g + 4);
        float4 f2 = *(const float4*)(g + 8);
        float4 f3 = *(const float4*)(g + 12);
        short8 c0, c1;
        c0[0]=(short)f2bf(f0.x); c0[1]=(short)f2bf(f0.y); c0[2]=(short)f2bf(f0.z); c0[3]=(short)f2bf(f0.w);
        c0[4]=(short)f2bf(f1.x); c0[5]=(short)f2bf(f1.y); c0[6]=(short)f2bf(f1.z); c0[7]=(short)f2bf(f1.w);
        c1[0]=(short)f2bf(f2.x); c1[1]=(short)f2bf(f2.y); c1[2]=(short)f2bf(f2.z); c1[3]=(short)f2bf(f2.w);
        c1[4]=(short)f2bf(f3.x); c1[5]=(short)f2bf(f3.y); c1[6]=(short)f2bf(f3.z); c1[7]=(short)f2bf(f3.w);
        int sw = l & 7;
        *(short8*)(sm + LDS_U + l * 256 + (((kc0    ) ^ sw) << 4)) = c0;
        *(short8*)(sm + LDS_U + l * 256 + (((kc0 + 1) ^ sw) << 4)) = c1;
    }
    __syncthreads();

    f32x4 acc2[2][2];   // GEMM2 accumulators (PASS==2), persist across halves
    if constexpr (PASS == 2) {
        #pragma unroll
        for (int i = 0; i < 2; i++)
            #pragma unroll
            for (int j = 0; j < 2; j++) acc2[i][j] = (f32x4)(0.0f);
    }

    for (int half = 0; half < 2; ++half) {
        // ---- GEMM1: acc[2M][4N] over K=128 ----
        f32x4 acc[2][4];
        #pragma unroll
        for (int i = 0; i < 2; i++)
            #pragma unroll
            for (int j = 0; j < 4; j++) acc[i][j] = (f32x4)(0.0f);

        int r = lane & 15, q = lane >> 4;
        #pragma unroll
        for (int kt = 0; kt < 4; ++kt) {
            short8 a[2];
            #pragma unroll
            for (int mf = 0; mf < 2; ++mf) {
                int la = wm * 32 + mf * 16 + r;
                int kc = kt * 4 + q;
                a[mf] = *(const short8*)(sm + LDS_U + la * 256 + ((kc ^ (la & 7)) << 4));
            }
            #pragma unroll
            for (int nfi = 0; nfi < 4; ++nfi) {
                int nfg = half * 16 + wn * 4 + nfi;
                short8 bb = *(const short8*)(BF + (size_t)((kt * 32 + nfg) * 64 + lane) * 8);
                acc[0][nfi] = mfma16(a[0], bb, acc[0][nfi]);
                acc[1][nfi] = mfma16(a[1], bb, acc[1][nfi]);
            }
        }

        __syncthreads();   // previous-half BU readers done
        // ---- acc -> BU[l][n] (pad 260) ----
        #pragma unroll
        for (int mf = 0; mf < 2; ++mf)
            #pragma unroll
            for (int nfi = 0; nfi < 4; ++nfi)
                #pragma unroll
                for (int j = 0; j < 4; ++j) {
                    int l  = wm * 32 + mf * 16 + (lane >> 4) * 4 + j;
                    int nn = wn * 64 + nfi * 16 + (lane & 15);
                    BU[l * 260 + nn] = acc[mf][nfi][j];
                }
        __syncthreads();

        // ---- scan (256 channels of this half, 1 thread each) ----
        if (tid < 256) {
            int n = tid, ng = half * 256 + n, p = ng >> 1;
            float m11 = cf[p],        m12 = cf[256 + p];
            float m21 = cf[512 + p],  m22 = cf[768 + p];
            float s1  = cf[1024 + p], s2  = cf[1280 + p];
            float x1, x2;
            if constexpr (PASS == 1) { x1 = 0.f; x2 = 0.f; }
            else { float2 iv = ini[(size_t)bc * 512 + ng]; x1 = iv.x; x2 = iv.y; }
            if constexpr (PASS == 1) {
                #pragma unroll 4
                for (int l = 0; l < CL; ++l) {
                    float f  = BU[l * 260 + n];
                    float n1 = fmaf(m11, x1, fmaf(m12, x2, s1 * f));
                    float n2 = fmaf(m21, x1, fmaf(m22, x2, s2 * f));
                    x1 = n1; x2 = n2;
                }
                loc[(size_t)bc * 512 + ng] = make_float2(x1, x2);
            } else {
                unsigned kc = n >> 3, e = n & 7;
                #pragma unroll 4
                for (int l = 0; l < CL; ++l) {
                    float f  = BU[l * 260 + n];
                    float n1 = fmaf(m11, x1, fmaf(m12, x2, s1 * f));
                    float n2 = fmaf(m21, x1, fmaf(m22, x2, s2 * f));
                    x1 = n1; x2 = n2;
                    *(unsigned short*)(sm + LDS_XS + l * 512 + ((kc ^ (unsigned)(l & 7)) << 4) + e * 2)
                        = f2bf(x2);
                }
            }
        }

        if constexpr (PASS == 2) {
            __syncthreads();
            // ---- GEMM2 partial: acc2 += XS_half (64x256) * CF'_half (256x128) ----
            #pragma unroll
            for (int kt = 0; kt < 8; ++kt) {
                short8 a2[2];
                #pragma unroll
                for (int mf = 0; mf < 2; ++mf) {
                    int la  = wm * 32 + mf * 16 + r;
                    int kc2 = kt * 4 + q;
                    a2[mf] = *(const short8*)(sm + LDS_XS + la * 512 + ((kc2 ^ (la & 7)) << 4));
                }
                #pragma unroll
                for (int nfi = 0; nfi < 2; ++nfi) {
                    int ktG = half * 8 + kt;
                    int nfg = wn * 2 + nfi;
                    short8 bb = *(const short8*)(CFr + (size_t)((ktG * 8 + nfg) * 64 + lane) * 8);
                    acc2[0][nfi] = mfma16(a2[0], bb, acc2[0][nfi]);
                    acc2[1][nfi] = mfma16(a2[1], bb, acc2[1][nfi]);
                }
            }
            __syncthreads();   // XS/BU reuse protection for next half
        }
    }

    // ---- epilogue (PASS 2): out = acc2 + in*D ----
    if constexpr (PASS == 2) {
        #pragma unroll
        for (int nfi = 0; nfi < 2; ++nfi) {
            int h = wn * 32 + nfi * 16 + (lane & 15);
            float d = Dw[h];
            #pragma unroll
            for (int mf = 0; mf < 2; ++mf)
                #pragma unroll
                for (int j = 0; j < 4; ++j) {
                    int l = wm * 32 + mf * 16 + (lane >> 4) * 4 + j;
                    size_t gm = mbase + l;
                    out[gm * Hc + h] = acc2[mf][nfi][j] + in[gm * Hc + h] * d;
                }
        }
    }
}

// ---------------------------------------------------------------- launch
extern "C" void kernel_launch(void* const* d_in, const int* in_sizes, int n_in,
                              void* d_out, int out_size, void* d_ws, size_t ws_size,
                              hipStream_t stream) {
    const float* in  = (const float*)d_in[0];
    const float* Ad  = (const float*)d_in[1];
    const float* Bw  = (const float*)d_in[2];
    const float* Cw  = (const float*)d_in[3];
    const float* Dw  = (const float*)d_in[4];
    const float* stp = (const float*)d_in[5];
    char* ws = (char*)d_ws;
    float*          cf  = (float*)(ws + CF_OFF);
    unsigned short* BF  = (unsigned short*)(ws + BF_OFF);
    unsigned short* CFr = (unsigned short*)(ws + CFR_OFF);
    float2*         loc = (float2*)(ws + LOC_OFF);
    float2*         ini = (float2*)(ws + INI_OFF);
    float* out = (float*)d_out;

    k_prep<<<256, 256, 0, stream>>>(Ad, stp, Bw, Cw, cf, BF, CFr);
    k_pass<1><<<BTc * NC, 512, 0, stream>>>(in, cf, BF, CFr, Dw, loc, ini, out);
    k_scanB<<<BTc, 512, 0, stream>>>(cf, loc, ini);
    k_pass<2><<<BTc * NC, 512, 0, stream>>>(in, cf, BF, CFr, Dw, loc, ini, out);
}

// Round 4
// 150.895 us; speedup vs baseline: 2.6946x; 1.1394x over previous
//
#include <hip/hip_runtime.h>
#include <math.h>

// LinOSS layer (IM), fused MFMA pipeline v2. Bt=16, L=4096, H=128, P=256.
// Per (b,chunk) block: stage U(bf16) -> GEMM1 (both halves) -> unified bf16
// BUX buffers (swizzled) -> 512-thread scan (in-place x2 on pass2) -> GEMM2.
// LDS 80KB -> 2 blocks/CU.

constexpr int BTc = 16;
constexpr int Lc  = 4096;
constexpr int Hc  = 128;
constexpr int Pc  = 256;
constexpr int CL  = 64;
constexpr int NC  = Lc / CL;   // 64
constexpr int LOG2CL = 6;

typedef __attribute__((ext_vector_type(8))) short short8;
typedef __attribute__((ext_vector_type(4))) float f32x4;

// workspace byte offsets
constexpr size_t CF_OFF  = 0;                  // 10*256 floats used
constexpr size_t BF_OFF  = 16384;              // 65536 bf16: GEMM1 B frags
constexpr size_t CFR_OFF = BF_OFF + 131072;    // 65536 bf16: GEMM2 C' frags
constexpr size_t LOC_OFF = CFR_OFF + 131072;   // 16*64*512 float2 (4 MB)
constexpr size_t INI_OFF = LOC_OFF + 4194304;  // 4 MB

// LDS: U bf16 [64][128] swz (16KB) | BUX0 (32KB) | BUX1 (32KB)  = 80KB
constexpr int LDS_U   = 0;
constexpr int LDS_BUX = 16384;
constexpr int LDS_BYTES = 81920;

__device__ __forceinline__ unsigned short f2bf(float x) {
    unsigned u = __float_as_uint(x);
    u += 0x7fffu + ((u >> 16) & 1u);          // RNE
    return (unsigned short)(u >> 16);
}
__device__ __forceinline__ float bf2f(unsigned short h) {
    return __uint_as_float(((unsigned)h) << 16);
}
__device__ __forceinline__ f32x4 mfma16(short8 a, short8 b, f32x4 c) {
    return __builtin_amdgcn_mfma_f32_16x16x32_bf16(a, b, c, 0, 0, 0);
}
__device__ __forceinline__ int swz(int l) { return (l ^ (l >> 3)) & 7; }

// ---------------------------------------------------------------- prep
__global__ __launch_bounds__(256) void k_prep(const float* __restrict__ A_diag,
                                              const float* __restrict__ steps,
                                              const float* __restrict__ Bw,
                                              const float* __restrict__ Cw,
                                              float* __restrict__ cf,
                                              unsigned short* __restrict__ BF,
                                              unsigned short* __restrict__ CFr) {
    int idx = blockIdx.x * 256 + threadIdx.x;   // 0..65535
    {   // GEMM1 B fragments: col n = 2p+part (512), k = h (128)
        int j = idx & 7, lane = (idx >> 3) & 63, nfg = (idx >> 9) & 31, kt = idx >> 14;
        int k = kt * 32 + (lane >> 4) * 8 + j;
        int n = nfg * 16 + (lane & 15);
        int p = n >> 1, part = n & 1;
        BF[idx] = f2bf(Bw[(p * Hc + k) * 2 + part]);
    }
    {   // GEMM2 C' fragments: col h (128), k = channel 2p+part (512), -ci on im
        int j = idx & 7, lane = (idx >> 3) & 63, nfg = (idx >> 9) & 7, ktG = idx >> 12;
        int k = ktG * 32 + (lane >> 4) * 8 + j;
        int h = nfg * 16 + (lane & 15);
        int p = k >> 1, part = k & 1;
        float v = Cw[(h * Pc + p) * 2 + part];
        CFr[idx] = f2bf(part ? -v : v);
    }
    if (blockIdx.x == 0) {
        int p = threadIdx.x;
        float a  = fmaxf(A_diag[p], 0.0f);
        float st = 1.0f / (1.0f + expf(-steps[p]));
        float s2a   = st * st * a;
        float schur = 1.0f / (1.0f + s2a);
        float m11 = 1.0f - s2a * schur;
        float m12 = -st * a * schur;
        float m21 = st * schur;
        float m22 = schur;
        cf[0*Pc+p] = m11;  cf[1*Pc+p] = m12;
        cf[2*Pc+p] = m21;  cf[3*Pc+p] = m22;
        cf[4*Pc+p] = m11 * st;   // s1
        cf[5*Pc+p] = m21 * st;   // s2
        float a11=m11, a12=m12, a21=m21, a22=m22;
        #pragma unroll
        for (int i = 0; i < LOG2CL; i++) {
            float b11 = a11*a11 + a12*a21;
            float b12 = a11*a12 + a12*a22;
            float b21 = a21*a11 + a22*a21;
            float b22 = a21*a12 + a22*a22;
            a11=b11; a12=b12; a21=b21; a22=b22;
        }
        cf[6*Pc+p]=a11; cf[7*Pc+p]=a12; cf[8*Pc+p]=a21; cf[9*Pc+p]=a22;
    }
}

// ---------------------------------------------------------------- scan B
// 8-deep batched prefetch: one memory latency per 8 chunk steps.
__global__ __launch_bounds__(512) void k_scanB(const float* __restrict__ cf,
                                               const float2* __restrict__ loc,
                                               float2* __restrict__ ini) {
    int b = blockIdx.x, n = threadIdx.x;
    int p = n >> 1;
    float A11=cf[6*Pc+p], A12=cf[7*Pc+p], A21=cf[8*Pc+p], A22=cf[9*Pc+p];
    float x1 = 0.f, x2 = 0.f;
    for (int g = 0; g < 8; g++) {
        float2 lv[8];
        #pragma unroll
        for (int j = 0; j < 8; j++)
            lv[j] = loc[((size_t)(b * NC + g * 8 + j)) * 512 + n];
        #pragma unroll
        for (int j = 0; j < 8; j++) {
            size_t idx = ((size_t)(b * NC + g * 8 + j)) * 512 + n;
            ini[idx] = make_float2(x1, x2);
            float n1 = fmaf(A11, x1, fmaf(A12, x2, lv[j].x));
            float n2 = fmaf(A21, x1, fmaf(A22, x2, lv[j].y));
            x1 = n1; x2 = n2;
        }
    }
}

// ---------------------------------------------------------------- fused pass
template<int PASS>
__global__ __launch_bounds__(512, 4) void k_pass(const float* __restrict__ in,
                                                 const float* __restrict__ cf,
                                                 const unsigned short* __restrict__ BF,
                                                 const unsigned short* __restrict__ CFr,
                                                 const float* __restrict__ Dw,
                                                 float2* __restrict__ loc,
                                                 const float2* __restrict__ ini,
                                                 float* __restrict__ out) {
    __shared__ float4 smem4[LDS_BYTES / 16];
    char* sm = (char*)smem4;

    int tid  = threadIdx.x;
    int lane = tid & 63;
    int w    = tid >> 6;
    int wm   = w >> 2, wn = w & 3;        // 2M x 4N wave grid
    int bc   = blockIdx.x;                // b*64 + c
    size_t mbase = (size_t)bc * CL;
    int r = lane & 15, q = lane >> 4;

    // ---- stage U: in f32 -> bf16, chunk16 xor (l&7) swizzle ----
    {
        int l   = tid >> 3;
        int kc0 = (tid & 7) * 2;
        const float* g = in + (mbase + l) * Hc + (tid & 7) * 16;
        float4 f0 = *(const float4*)(g);
        float4 f1 = *(const float4*)(g + 4);
        float4 f2 = *(const float4*)(g + 8);
        float4 f3 = *(const float4*)(g + 12);
        short8 c0, c1;
        c0[0]=(short)f2bf(f0.x); c0[1]=(short)f2bf(f0.y); c0[2]=(short)f2bf(f0.z); c0[3]=(short)f2bf(f0.w);
        c0[4]=(short)f2bf(f1.x); c0[5]=(short)f2bf(f1.y); c0[6]=(short)f2bf(f1.z); c0[7]=(short)f2bf(f1.w);
        c1[0]=(short)f2bf(f2.x); c1[1]=(short)f2bf(f2.y); c1[2]=(short)f2bf(f2.z); c1[3]=(short)f2bf(f2.w);
        c1[4]=(short)f2bf(f3.x); c1[5]=(short)f2bf(f3.y); c1[6]=(short)f2bf(f3.z); c1[7]=(short)f2bf(f3.w);
        int sw = l & 7;
        *(short8*)(sm + LDS_U + l * 256 + (((kc0    ) ^ sw) << 4)) = c0;
        *(short8*)(sm + LDS_U + l * 256 + (((kc0 + 1) ^ sw) << 4)) = c1;
    }
    __syncthreads();

    // ---- GEMM1 both halves -> BUX[half] (bf16, swizzled) ----
    #pragma unroll
    for (int half = 0; half < 2; ++half) {
        f32x4 acc[2][4];
        #pragma unroll
        for (int i = 0; i < 2; i++)
            #pragma unroll
            for (int j = 0; j < 4; j++) acc[i][j] = (f32x4)(0.0f);

        #pragma unroll
        for (int kt = 0; kt < 4; ++kt) {
            short8 a[2];
            #pragma unroll
            for (int mf = 0; mf < 2; ++mf) {
                int la = wm * 32 + mf * 16 + r;
                int kc = kt * 4 + q;
                a[mf] = *(const short8*)(sm + LDS_U + la * 256 + ((kc ^ (la & 7)) << 4));
            }
            #pragma unroll
            for (int nfi = 0; nfi < 4; ++nfi) {
                int nfg = half * 16 + wn * 4 + nfi;
                short8 bb = *(const short8*)(BF + (size_t)((kt * 32 + nfg) * 64 + lane) * 8);
                acc[0][nfi] = mfma16(a[0], bb, acc[0][nfi]);
                acc[1][nfi] = mfma16(a[1], bb, acc[1][nfi]);
            }
        }
        // write acc -> BUX[half] as bf16 in unified swizzled layout
        char* bux = sm + LDS_BUX + half * 32768;
        #pragma unroll
        for (int mf = 0; mf < 2; ++mf)
            #pragma unroll
            for (int nfi = 0; nfi < 4; ++nfi) {
                int nn = wn * 64 + nfi * 16 + r;
                int kc = nn >> 3, e = nn & 7;
                #pragma unroll
                for (int j = 0; j < 4; ++j) {
                    int l = wm * 32 + mf * 16 + q * 4 + j;
                    *(unsigned short*)(bux + l * 512 + ((kc ^ swz(l)) << 4) + e * 2)
                        = f2bf(acc[mf][nfi][j]);
                }
            }
    }
    __syncthreads();

    // ---- scan: all 512 threads, one global channel each ----
    {
        int ng = tid, h = ng >> 8, n = ng & 255, p = ng >> 1;
        float m11 = cf[p],        m12 = cf[256 + p];
        float m21 = cf[512 + p],  m22 = cf[768 + p];
        float s1  = cf[1024 + p], s2  = cf[1280 + p];
        float x1, x2;
        if constexpr (PASS == 1) { x1 = 0.f; x2 = 0.f; }
        else { float2 iv = ini[(size_t)bc * 512 + ng]; x1 = iv.x; x2 = iv.y; }
        char* bux = sm + LDS_BUX + h * 32768 + (n & 7) * 2;
        int kc = n >> 3;
        #pragma unroll 4
        for (int l = 0; l < CL; ++l) {
            char* addr = bux + l * 512 + ((kc ^ swz(l)) << 4);
            float f  = bf2f(*(unsigned short*)addr);
            float n1 = fmaf(m11, x1, fmaf(m12, x2, s1 * f));
            float n2 = fmaf(m21, x1, fmaf(m22, x2, s2 * f));
            x1 = n1; x2 = n2;
            if constexpr (PASS == 2) *(unsigned short*)addr = f2bf(x2);
        }
        if constexpr (PASS == 1) loc[(size_t)bc * 512 + ng] = make_float2(x1, x2);
    }

    if constexpr (PASS == 2) {
        __syncthreads();
        // ---- GEMM2: out-tile 64x128, K=512 (x2 bf16 in BUX) ----
        f32x4 acc2[2][2];
        #pragma unroll
        for (int i = 0; i < 2; i++)
            #pragma unroll
            for (int j = 0; j < 2; j++) acc2[i][j] = (f32x4)(0.0f);

        #pragma unroll
        for (int half = 0; half < 2; ++half) {
            char* bux = sm + LDS_BUX + half * 32768;
            #pragma unroll
            for (int kt = 0; kt < 8; ++kt) {
                short8 a2[2];
                #pragma unroll
                for (int mf = 0; mf < 2; ++mf) {
                    int la  = wm * 32 + mf * 16 + r;
                    int kc2 = kt * 4 + q;
                    a2[mf] = *(const short8*)(bux + la * 512 + ((kc2 ^ swz(la)) << 4));
                }
                #pragma unroll
                for (int nfi = 0; nfi < 2; ++nfi) {
                    int ktG = half * 8 + kt;
                    int nfg = wn * 2 + nfi;
                    short8 bb = *(const short8*)(CFr + (size_t)((ktG * 8 + nfg) * 64 + lane) * 8);
                    acc2[0][nfi] = mfma16(a2[0], bb, acc2[0][nfi]);
                    acc2[1][nfi] = mfma16(a2[1], bb, acc2[1][nfi]);
                }
            }
        }
        // epilogue: out = acc2 + in*D
        #pragma unroll
        for (int nfi = 0; nfi < 2; ++nfi) {
            int h = wn * 32 + nfi * 16 + r;
            float d = Dw[h];
            #pragma unroll
            for (int mf = 0; mf < 2; ++mf)
                #pragma unroll
                for (int j = 0; j < 4; ++j) {
                    int l = wm * 32 + mf * 16 + q * 4 + j;
                    size_t gm = mbase + l;
                    out[gm * Hc + h] = fmaf(in[gm * Hc + h], d, acc2[mf][nfi][j]);
                }
        }
    }
}

// ---------------------------------------------------------------- launch
extern "C" void kernel_launch(void* const* d_in, const int* in_sizes, int n_in,
                              void* d_out, int out_size, void* d_ws, size_t ws_size,
                              hipStream_t stream) {
    const float* in  = (const float*)d_in[0];
    const float* Ad  = (const float*)d_in[1];
    const float* Bw  = (const float*)d_in[2];
    const float* Cw  = (const float*)d_in[3];
    const float* Dw  = (const float*)d_in[4];
    const float* stp = (const float*)d_in[5];
    char* ws = (char*)d_ws;
    float*          cf  = (float*)(ws + CF_OFF);
    unsigned short* BF  = (unsigned short*)(ws + BF_OFF);
    unsigned short* CFr = (unsigned short*)(ws + CFR_OFF);
    float2*         loc = (float2*)(ws + LOC_OFF);
    float2*         ini = (float2*)(ws + INI_OFF);
    float* out = (float*)d_out;

    k_prep<<<256, 256, 0, stream>>>(Ad, stp, Bw, Cw, cf, BF, CFr);
    k_pass<1><<<BTc * NC, 512, 0, stream>>>(in, cf, BF, CFr, Dw, loc, ini, out);
    k_scanB<<<BTc, 512, 0, stream>>>(cf, loc, ini);
    k_pass<2><<<BTc * NC, 512, 0, stream>>>(in, cf, BF, CFr, Dw, loc, ini, out);
}